// Round 18
// baseline (51.614 us; speedup 1.0000x reference)
//
#include <hip/hip_runtime.h>

#define B_N    1024
#define F_DIMC 768
#define M_DIM  512
#define C_N    100
#define KSTEP  64
#define NSTEP  (F_DIMC / KSTEP)   // 12 k-steps
#define NGEMM  512                // 32 row-tiles x 16 col-tiles (32x32 out)
#define NIDX   25                 // 25 blocks x 4 waves = 100 classes

typedef float f32x4 __attribute__((ext_vector_type(4)));
typedef short s16x8 __attribute__((ext_vector_type(8)));

__device__ __forceinline__ unsigned int f2bf(float x) {
  unsigned int u = __builtin_bit_cast(unsigned int, x);
  return (u + 0x7fffu + ((u >> 16) & 1u)) >> 16;
}
__device__ __forceinline__ float bf2f(unsigned int h) {
  return __builtin_bit_cast(float, h << 16);
}

// ---------------------------------------------------------------------------
// Kernel 1: MFMA gemm feat = relu(X@W), split-bf16 3-term, BK=64 (12 steps,
// latency amortized 2x vs R15) + ballot-rank index build.
// Same 24 K=32 MFMAs in identical order as R15 -> bit-identical feat.
// ---------------------------------------------------------------------------
__global__ __launch_bounds__(256) void gemm_index_kernel(
    const float* __restrict__ X, const float* __restrict__ W,
    const int* __restrict__ labels, float* __restrict__ feat,
    int* __restrict__ counts, int* __restrict__ idx) {
  __shared__ unsigned short Ah[2][32][72], Al[2][32][72];  // [row][k] pad->72
  __shared__ unsigned short Bh[2][32][72], Bl[2][32][72];  // [col][k] pad->72
  __shared__ int lab[B_N];

  const int t = threadIdx.x;
  const int b = (int)blockIdx.x;

  if (b >= NGEMM) {  // ---- index path ----
    for (int i = t; i < B_N; i += 256) lab[i] = labels[i];
    __syncthreads();
    const int w    = t >> 6;
    const int lane = t & 63;
    const int c    = (b - NGEMM) * 4 + w;
    if (c < C_N) {
      int base = 0;
      for (int ch = 0; ch < 16; ++ch) {
        const int j = ch * 64 + lane;
        const bool hit = (lab[j] == c);
        const unsigned long long mask = __ballot(hit);
        if (hit) {
          const int r = __popcll(mask & ((1ull << lane) - 1ull));
          idx[c * B_N + base + r] = j;
        }
        base += __popcll(mask);
      }
      if (lane == 0) counts[c] = base;
    }
    return;
  }

  // ---- MFMA gemm path ----
  const int bm = (b >> 4) * 32;
  const int bn = (b & 15) * 32;

  // staging roles: threads 0..127 stage X (32r x 64k, 16 f32 each);
  //                threads 128..255 stage W (64k x 32c, 16 f32 each).
  const bool isX = (t < 128);
  const int xr = t >> 2;              // 0..31 row
  const int xk = (t & 3) * 16;        // 0,16,32,48 k-offset
  const int uu = isX ? 0 : (t - 128); // 0..127
  const int wk = (uu >> 3) * 4;       // 0..60 (4 k-rows)
  const int wc = (uu & 7) * 4;        // 0..28 col base

  const float* __restrict__ Xp = X + (size_t)(bm + xr) * F_DIMC + xk;
  const float* __restrict__ Wp = W + (size_t)wk * M_DIM + bn + wc;

  // compute roles: wave wv owns 16x16 subtile (m0, n0)
  const int lane = t & 63;
  const int wv   = t >> 6;
  const int m0 = (wv & 1) * 16;
  const int n0 = (wv >> 1) * 16;
  const int fr = lane & 15;
  const int fq = (lane >> 4) * 8;

  f32x4 acc = {0.f, 0.f, 0.f, 0.f};

  float4 r0, r1, r2, r3;
  auto LOAD = [&](int k0) {
    if (isX) {
      r0 = *(const float4*)(Xp + k0);
      r1 = *(const float4*)(Xp + k0 + 4);
      r2 = *(const float4*)(Xp + k0 + 8);
      r3 = *(const float4*)(Xp + k0 + 12);
    } else {
      r0 = *(const float4*)(Wp + (size_t)(k0 + 0) * M_DIM);
      r1 = *(const float4*)(Wp + (size_t)(k0 + 1) * M_DIM);
      r2 = *(const float4*)(Wp + (size_t)(k0 + 2) * M_DIM);
      r3 = *(const float4*)(Wp + (size_t)(k0 + 3) * M_DIM);
    }
  };

  auto STAGE = [&](int buf) {
    if (isX) {
      const float v[16] = {r0.x, r0.y, r0.z, r0.w, r1.x, r1.y, r1.z, r1.w,
                           r2.x, r2.y, r2.z, r2.w, r3.x, r3.y, r3.z, r3.w};
      s16x8 hv0, lv0, hv1, lv1;
#pragma unroll
      for (int j = 0; j < 8; ++j) {
        unsigned int hb = f2bf(v[j]);
        hv0[j] = (short)hb;
        lv0[j] = (short)f2bf(v[j] - bf2f(hb));
        hb = f2bf(v[j + 8]);
        hv1[j] = (short)hb;
        lv1[j] = (short)f2bf(v[j + 8] - bf2f(hb));
      }
      *(s16x8*)&Ah[buf][xr][xk]     = hv0;
      *(s16x8*)&Ah[buf][xr][xk + 8] = hv1;
      *(s16x8*)&Al[buf][xr][xk]     = lv0;
      *(s16x8*)&Al[buf][xr][xk + 8] = lv1;
    } else {
      const float a[4] = {r0.x, r0.y, r0.z, r0.w};   // k = wk
      const float d[4] = {r1.x, r1.y, r1.z, r1.w};   // k = wk+1
      const float e[4] = {r2.x, r2.y, r2.z, r2.w};   // k = wk+2
      const float g[4] = {r3.x, r3.y, r3.z, r3.w};   // k = wk+3
#pragma unroll
      for (int i = 0; i < 4; ++i) {
        unsigned int ha = f2bf(a[i]), hd = f2bf(d[i]);
        unsigned int la = f2bf(a[i] - bf2f(ha)), ld = f2bf(d[i] - bf2f(hd));
        *(unsigned int*)&Bh[buf][wc + i][wk]     = ha | (hd << 16);
        *(unsigned int*)&Bl[buf][wc + i][wk]     = la | (ld << 16);
        unsigned int he = f2bf(e[i]), hg = f2bf(g[i]);
        unsigned int le = f2bf(e[i] - bf2f(he)), lg = f2bf(g[i] - bf2f(hg));
        *(unsigned int*)&Bh[buf][wc + i][wk + 2] = he | (hg << 16);
        *(unsigned int*)&Bl[buf][wc + i][wk + 2] = le | (lg << 16);
      }
    }
  };

  LOAD(0);
  STAGE(0);
  __syncthreads();

  for (int it = 0; it < NSTEP; ++it) {
    const int cur = it & 1;
    if (it + 1 < NSTEP) LOAD((it + 1) * KSTEP);
#pragma unroll
    for (int kh = 0; kh < 2; ++kh) {
      const int ko = kh * 32 + fq;
      const s16x8 ah = *(const s16x8*)&Ah[cur][m0 + fr][ko];
      const s16x8 al = *(const s16x8*)&Al[cur][m0 + fr][ko];
      const s16x8 bh = *(const s16x8*)&Bh[cur][n0 + fr][ko];
      const s16x8 bl = *(const s16x8*)&Bl[cur][n0 + fr][ko];
      acc = __builtin_amdgcn_mfma_f32_16x16x32_bf16(ah, bh, acc, 0, 0, 0);
      acc = __builtin_amdgcn_mfma_f32_16x16x32_bf16(al, bh, acc, 0, 0, 0);
      acc = __builtin_amdgcn_mfma_f32_16x16x32_bf16(ah, bl, acc, 0, 0, 0);
    }
    if (it + 1 < NSTEP) STAGE(cur ^ 1);
    __syncthreads();
  }

  const int rr0 = (lane >> 4) * 4;
#pragma unroll
  for (int r = 0; r < 4; ++r)
    feat[(size_t)(bm + m0 + rr0 + r) * M_DIM + bn + n0 + fr] =
        fmaxf(acc[r], 0.0f);
}

// ---------------------------------------------------------------------------
// Kernel 2: phi 64-row panels + mu/count.
// grid = (9, C): x<8 -> 64 rows x 512 cols of phi[c] (acc[16][8]/thread);
// x==8 -> mu/count. Staging passes per class: 9 (vs 17 in R15).
// av = 4x b128 wave-broadcast; bv = 2x b128 lane-contiguous; nt f32x4 stores.
// ---------------------------------------------------------------------------
__global__ __launch_bounds__(256) void phi_mu_kernel(
    const float* __restrict__ feat, const int* __restrict__ counts,
    const int* __restrict__ idx, float* __restrict__ phi,
    float* __restrict__ mu, float* __restrict__ cnt_out) {
  const int c = blockIdx.y;
  const int n = counts[c];
  const int* __restrict__ id = idx + c * B_N;
  const int t = threadIdx.x;

  if (blockIdx.x == 8) {  // ---- mu / count path ----
    float2 acc = make_float2(0.f, 0.f);
    for (int s = 0; s < n; ++s) {
      const float2 q = *(const float2*)&feat[(size_t)id[s] * M_DIM + t * 2];
      acc.x += q.x;
      acc.y += q.y;
    }
    *(float2*)&mu[(size_t)c * M_DIM + t * 2] = acc;
    if (t == 0) cnt_out[c] = (float)n;
    return;
  }

  // ---- phi panel: rows 64*px..+64, all 512 cols ----
  const int px = (int)blockIdx.x;      // 0..7
  const int tr = t >> 6;               // wave id -> 16-row group
  const int tc = t & 63;               // cols tc*4 and 256+tc*4

  __shared__ float F[16][M_DIM];

  float acc[16][8] = {};

  for (int s0 = 0; s0 < n; s0 += 16) {
    const int chunk  = min(16, n - s0);
    if (s0) __syncthreads();           // protect F before overwrite
    const int nslots = chunk << 7;     // chunk * 128 float4 per row
    for (int v = t; v < nslots; v += 256) {
      const int sl = v >> 7;
      const int fp = (v & 127) << 2;
      *(float4*)&F[sl][fp] =
          *(const float4*)&feat[(size_t)id[s0 + sl] * M_DIM + fp];
    }
    __syncthreads();
    for (int sl = 0; sl < chunk; ++sl) {
      const int ab = px * 64 + tr * 16;
      const float4 a0 = *(const float4*)&F[sl][ab];        // bcast
      const float4 a1 = *(const float4*)&F[sl][ab + 4];    // bcast
      const float4 a2 = *(const float4*)&F[sl][ab + 8];    // bcast
      const float4 a3 = *(const float4*)&F[sl][ab + 12];   // bcast
      const float4 b0 = *(const float4*)&F[sl][tc * 4];        // contig
      const float4 b1 = *(const float4*)&F[sl][256 + tc * 4];  // contig
      const float av[16] = {a0.x, a0.y, a0.z, a0.w, a1.x, a1.y, a1.z, a1.w,
                            a2.x, a2.y, a2.z, a2.w, a3.x, a3.y, a3.z, a3.w};
      const float bv[8]  = {b0.x, b0.y, b0.z, b0.w, b1.x, b1.y, b1.z, b1.w};
#pragma unroll
      for (int r = 0; r < 16; ++r)
#pragma unroll
        for (int q = 0; q < 8; ++q)
          acc[r][q] += av[r] * bv[q];
    }
  }

  float* __restrict__ out = phi + (size_t)c * M_DIM * M_DIM;
#pragma unroll
  for (int r = 0; r < 16; ++r) {
    const size_t row = (size_t)(px * 64 + tr * 16 + r) * M_DIM;
    const f32x4 o0 = {acc[r][0], acc[r][1], acc[r][2], acc[r][3]};
    const f32x4 o1 = {acc[r][4], acc[r][5], acc[r][6], acc[r][7]};
    __builtin_nontemporal_store(o0, (f32x4*)&out[row + tc * 4]);
    __builtin_nontemporal_store(o1, (f32x4*)&out[row + 256 + tc * 4]);
  }
}

// ---------------------------------------------------------------------------
extern "C" void kernel_launch(void* const* d_in, const int* in_sizes, int n_in,
                              void* d_out, int out_size, void* d_ws,
                              size_t ws_size, hipStream_t stream) {
  const float* X      = (const float*)d_in[0];
  const float* W      = (const float*)d_in[1];
  const int*   labels = (const int*)d_in[2];

  float* out = (float*)d_out;
  float* phi = out;                                // C*M*M
  float* mu  = out + (size_t)C_N * M_DIM * M_DIM;  // C*M
  float* cnt = mu + (size_t)C_N * M_DIM;           // C

  float* feat   = (float*)d_ws;                    // B*M fp32 = 2 MB
  int*   counts = (int*)((char*)d_ws + (size_t)B_N * M_DIM * sizeof(float));
  int*   idx    = counts + 128;                    // C*B ints

  hipLaunchKernelGGL(gemm_index_kernel, dim3(NGEMM + NIDX), dim3(256), 0,
                     stream, X, W, labels, feat, counts, idx);
  hipLaunchKernelGGL(phi_mu_kernel, dim3(9, C_N), dim3(256), 0, stream,
                     feat, counts, idx, phi, mu, cnt);
}

// Round 19
// 41.414 us; speedup vs baseline: 1.2463x; 1.2463x over previous
//
#include <hip/hip_runtime.h>

#define B_N    1024
#define F_DIMC 768
#define M_DIM  512
#define C_N    100
#define KSTEP  32
#define NSTEP  (F_DIMC / KSTEP)   // 24 k-steps
#define NGEMM  512                // 32 row-tiles x 16 col-tiles (32x32 out)
#define NIDX   25                 // 25 blocks x 4 waves = 100 classes

typedef float f32x4 __attribute__((ext_vector_type(4)));
typedef short s16x8 __attribute__((ext_vector_type(8)));

// v_cvt_pk_bf16_f32: dst[15:0] = bf16(lo), dst[31:16] = bf16(hi). RNE.
__device__ __forceinline__ unsigned int cvt_pk_bf16(float lo, float hi) {
  unsigned int r;
  asm("v_cvt_pk_bf16_f32 %0, %1, %2" : "=v"(r) : "v"(lo), "v"(hi));
  return r;
}

// ---------------------------------------------------------------------------
// Kernel 1: MFMA gemm feat = relu(X@W) (split-bf16, 3-term) + index build.
// R15 structure; staging conversions via v_cvt_pk_bf16_f32 (1 instr / 2
// elems for hi; extract+sub+cvt_pk for lo) instead of manual bit-RNE.
// ---------------------------------------------------------------------------
__global__ __launch_bounds__(256) void gemm_index_kernel(
    const float* __restrict__ X, const float* __restrict__ W,
    const int* __restrict__ labels, float* __restrict__ feat,
    int* __restrict__ counts, int* __restrict__ idx) {
  __shared__ unsigned short Ah[2][32][40], Al[2][32][40];  // [row][k] 80B pitch
  __shared__ unsigned short Bh[2][32][40], Bl[2][32][40];  // [col][k] 80B pitch
  __shared__ int lab[B_N];

  const int t = threadIdx.x;
  const int b = (int)blockIdx.x;

  if (b >= NGEMM) {  // ---- index path ----
    for (int i = t; i < B_N; i += 256) lab[i] = labels[i];
    __syncthreads();
    const int w    = t >> 6;
    const int lane = t & 63;
    const int c    = (b - NGEMM) * 4 + w;
    if (c < C_N) {
      int base = 0;
      for (int ch = 0; ch < 16; ++ch) {
        const int j = ch * 64 + lane;
        const bool hit = (lab[j] == c);
        const unsigned long long mask = __ballot(hit);
        if (hit) {
          const int r = __popcll(mask & ((1ull << lane) - 1ull));
          idx[c * B_N + base + r] = j;
        }
        base += __popcll(mask);
      }
      if (lane == 0) counts[c] = base;
    }
    return;
  }

  // ---- MFMA gemm path ----
  const int bm = (b >> 4) * 32;   // 32 row tiles
  const int bn = (b & 15) * 32;   // 16 col tiles

  // staging roles: waves 0,1 stage X (8 elems/thread); waves 2,3 stage W.
  const bool isX = (t < 128);
  const int xr = t >> 2;              // 0..31 row
  const int xk = (t & 3) * 8;         // 0,8,16,24 k-offset
  const int uu = isX ? 0 : (t - 128);
  const int wk = (uu >> 3) * 2;       // 0..30 even k
  const int wc = (uu & 7) * 4;        // 0..28 col base

  const float* __restrict__ Xp = X + (size_t)(bm + xr) * F_DIMC + xk;
  const float* __restrict__ Wp = W + (size_t)wk * M_DIM + bn + wc;

  // compute roles: wave wv owns 16x16 subtile (m0, n0)
  const int lane = t & 63;
  const int wv   = t >> 6;
  const int m0 = (wv & 1) * 16;
  const int n0 = (wv >> 1) * 16;
  const int fr = lane & 15;
  const int fq = (lane >> 4) * 8;

  f32x4 acc = {0.f, 0.f, 0.f, 0.f};

  float4 ra0, ra1, rb0, rb1;
  if (isX) {
    ra0 = *(const float4*)(Xp);
    ra1 = *(const float4*)(Xp + 4);
  } else {
    rb0 = *(const float4*)(Wp);
    rb1 = *(const float4*)(Wp + M_DIM);
  }

  auto STAGE = [&](int buf) {
    if (isX) {
      const float v[8] = {ra0.x, ra0.y, ra0.z, ra0.w,
                          ra1.x, ra1.y, ra1.z, ra1.w};
      unsigned int hu[4], lu[4];
#pragma unroll
      for (int j = 0; j < 4; ++j) {
        hu[j] = cvt_pk_bf16(v[2 * j], v[2 * j + 1]);
        const float l0 =
            v[2 * j] - __builtin_bit_cast(float, hu[j] << 16);
        const float l1 =
            v[2 * j + 1] - __builtin_bit_cast(float, hu[j] & 0xffff0000u);
        lu[j] = cvt_pk_bf16(l0, l1);
      }
      *(uint4*)&Ah[buf][xr][xk] = make_uint4(hu[0], hu[1], hu[2], hu[3]);
      *(uint4*)&Al[buf][xr][xk] = make_uint4(lu[0], lu[1], lu[2], lu[3]);
    } else {
      const float a[4] = {rb0.x, rb0.y, rb0.z, rb0.w};   // k = wk
      const float d[4] = {rb1.x, rb1.y, rb1.z, rb1.w};   // k = wk+1
#pragma unroll
      for (int i = 0; i < 4; ++i) {
        const unsigned int h = cvt_pk_bf16(a[i], d[i]);  // ha | hd<<16
        const float la = a[i] - __builtin_bit_cast(float, h << 16);
        const float ld = d[i] - __builtin_bit_cast(float, h & 0xffff0000u);
        const unsigned int l = cvt_pk_bf16(la, ld);
        *(unsigned int*)&Bh[buf][wc + i][wk] = h;
        *(unsigned int*)&Bl[buf][wc + i][wk] = l;
      }
    }
  };

  STAGE(0);
  __syncthreads();

  for (int it = 0; it < NSTEP; ++it) {
    const int cur = it & 1;
    if (it + 1 < NSTEP) {
      const int k0 = (it + 1) * KSTEP;
      if (isX) {
        ra0 = *(const float4*)(Xp + k0);
        ra1 = *(const float4*)(Xp + k0 + 4);
      } else {
        rb0 = *(const float4*)(Wp + (size_t)k0 * M_DIM);
        rb1 = *(const float4*)(Wp + (size_t)(k0 + 1) * M_DIM);
      }
    }
    const s16x8 ah = *(const s16x8*)&Ah[cur][m0 + fr][fq];
    const s16x8 al = *(const s16x8*)&Al[cur][m0 + fr][fq];
    const s16x8 bh = *(const s16x8*)&Bh[cur][n0 + fr][fq];
    const s16x8 bl = *(const s16x8*)&Bl[cur][n0 + fr][fq];
    acc = __builtin_amdgcn_mfma_f32_16x16x32_bf16(ah, bh, acc, 0, 0, 0);
    acc = __builtin_amdgcn_mfma_f32_16x16x32_bf16(al, bh, acc, 0, 0, 0);
    acc = __builtin_amdgcn_mfma_f32_16x16x32_bf16(ah, bl, acc, 0, 0, 0);
    if (it + 1 < NSTEP) STAGE(cur ^ 1);
    __syncthreads();
  }

  // store with relu; C layout (verified): col = lane&15, row = (lane>>4)*4+r
  const int r0 = (lane >> 4) * 4;
#pragma unroll
  for (int r = 0; r < 4; ++r)
    feat[(size_t)(bm + m0 + r0 + r) * M_DIM + bn + n0 + fr] =
        fmaxf(acc[r], 0.0f);
}

// ---------------------------------------------------------------------------
// Kernel 2 (R15 verbatim): phi 32-row panels + mu/count.
// grid = (17, C): panels 0..15 -> 32 rows x 512 cols; panel 16 -> mu/count.
// ---------------------------------------------------------------------------
__global__ __launch_bounds__(256, 4) void phi_mu_kernel(
    const float* __restrict__ feat, const int* __restrict__ counts,
    const int* __restrict__ idx, float* __restrict__ phi,
    float* __restrict__ mu, float* __restrict__ cnt_out) {
  const int c = blockIdx.y;
  const int n = counts[c];
  const int* __restrict__ id = idx + c * B_N;
  const int t = threadIdx.x;

  if (blockIdx.x == 16) {  // ---- mu / count path ----
    float2 acc = make_float2(0.f, 0.f);
    for (int s = 0; s < n; ++s) {
      const float2 q = *(const float2*)&feat[(size_t)id[s] * M_DIM + t * 2];
      acc.x += q.x;
      acc.y += q.y;
    }
    *(float2*)&mu[(size_t)c * M_DIM + t * 2] = acc;
    if (t == 0) cnt_out[c] = (float)n;
    return;
  }

  // ---- phi row-panel path: rows 32*px..+32, all 512 cols ----
  const int px = (int)blockIdx.x;      // 0..15
  const int tr = t >> 6;               // row group 0..3 (x8 rows)
  const int tc = t & 63;               // cols tc*4 and 256+tc*4

  __shared__ float F[16][M_DIM];

  float acc[8][8] = {};

  for (int s0 = 0; s0 < n; s0 += 16) {
    const int chunk  = min(16, n - s0);
    if (s0) __syncthreads();           // protect F before overwrite
    const int nslots = chunk << 7;     // chunk * 128 float4 per row
    for (int v = t; v < nslots; v += 256) {
      const int sl = v >> 7;
      const int fp = (v & 127) << 2;
      *(float4*)&F[sl][fp] =
          *(const float4*)&feat[(size_t)id[s0 + sl] * M_DIM + fp];
    }
    __syncthreads();
    for (int sl = 0; sl < chunk; ++sl) {
      const float4 a0 = *(const float4*)&F[sl][px * 32 + tr * 8];      // bcast
      const float4 a1 = *(const float4*)&F[sl][px * 32 + tr * 8 + 4];  // bcast
      const float4 b0 = *(const float4*)&F[sl][tc * 4];        // contiguous
      const float4 b1 = *(const float4*)&F[sl][256 + tc * 4];  // contiguous
      const float av[8] = {a0.x, a0.y, a0.z, a0.w, a1.x, a1.y, a1.z, a1.w};
      const float bv[8] = {b0.x, b0.y, b0.z, b0.w, b1.x, b1.y, b1.z, b1.w};
#pragma unroll
      for (int r = 0; r < 8; ++r)
#pragma unroll
        for (int q = 0; q < 8; ++q)
          acc[r][q] += av[r] * bv[q];
    }
  }

  float* __restrict__ out = phi + (size_t)c * M_DIM * M_DIM;
#pragma unroll
  for (int r = 0; r < 8; ++r) {
    const size_t row = (size_t)(px * 32 + tr * 8 + r) * M_DIM;
    const f32x4 o0 = {acc[r][0], acc[r][1], acc[r][2], acc[r][3]};
    const f32x4 o1 = {acc[r][4], acc[r][5], acc[r][6], acc[r][7]};
    __builtin_nontemporal_store(o0, (f32x4*)&out[row + tc * 4]);
    __builtin_nontemporal_store(o1, (f32x4*)&out[row + 256 + tc * 4]);
  }
}

// ---------------------------------------------------------------------------
extern "C" void kernel_launch(void* const* d_in, const int* in_sizes, int n_in,
                              void* d_out, int out_size, void* d_ws,
                              size_t ws_size, hipStream_t stream) {
  const float* X      = (const float*)d_in[0];
  const float* W      = (const float*)d_in[1];
  const int*   labels = (const int*)d_in[2];

  float* out = (float*)d_out;
  float* phi = out;                                // C*M*M
  float* mu  = out + (size_t)C_N * M_DIM * M_DIM;  // C*M
  float* cnt = mu + (size_t)C_N * M_DIM;           // C

  float* feat   = (float*)d_ws;                    // B*M fp32 = 2 MB
  int*   counts = (int*)((char*)d_ws + (size_t)B_N * M_DIM * sizeof(float));
  int*   idx    = counts + 128;                    // C*B ints

  hipLaunchKernelGGL(gemm_index_kernel, dim3(NGEMM + NIDX), dim3(256), 0,
                     stream, X, W, labels, feat, counts, idx);
  hipLaunchKernelGGL(phi_mu_kernel, dim3(17, C_N), dim3(256), 0, stream,
                     feat, counts, idx, phi, mu, cnt);
}